// Round 1
// baseline (1497.133 us; speedup 1.0000x reference)
//
#include <hip/hip_runtime.h>
#include <hip/hip_bf16.h>
#include <string.h>

#define H 256
#define K2 512
#define BM 64
#define THREADS 512
#define LTOT 65536

typedef __attribute__((ext_vector_type(8))) short short8;
typedef __attribute__((ext_vector_type(4))) float f32x4;

struct __align__(8) S4 { short x, y, z, w; };

__device__ __forceinline__ short f2bf(float f) {
    union { float f; unsigned u; } v; v.f = f;
    unsigned r = v.u + 0x7fffu + ((v.u >> 16) & 1u);
    return (short)(r >> 16);
}
__device__ __forceinline__ float bf2f(short s) {
    union { unsigned u; float f; } v; v.u = ((unsigned)(unsigned short)s) << 16;
    return v.f;
}
__device__ __forceinline__ float sigm(float x) {
    return 1.f / (1.f + __expf(-x));
}
__device__ __forceinline__ int swz(int row, int kbytes) {
    return ((row << 10) + kbytes) ^ ((row & 7) << 4);
}

// ---------------- weight/bias prep ----------------
__global__ void prep_kernel(const float* __restrict__ WL, const float* __restrict__ WR,
                            const float* __restrict__ Wlh, const float* __restrict__ Wrh,
                            const float* __restrict__ bL, const float* __restrict__ bR,
                            const float* __restrict__ blh, const float* __restrict__ brh,
                            short* __restrict__ W1, short* __restrict__ W2,
                            float* __restrict__ pb, float* __restrict__ hb) {
    int i = blockIdx.x * blockDim.x + threadIdx.x;
    const int nW1 = 5 * H * K2;
    if (i < nW1) {
        int g = i / (H * K2);
        int rem = i % (H * K2);
        int o = rem / K2, k = rem % K2;
        float v = (k < H) ? WL[(g * H + o) * H + k] : WR[(g * H + o) * H + (k - H)];
        W1[i] = f2bf(v);
        return;
    }
    int j = i - nW1;
    if (j < H * K2) {
        int o = j / K2, k = j % K2;
        float v = (k < H) ? Wlh[o * H + k] : Wrh[o * H + (k - H)];
        W2[j] = f2bf(v);
        return;
    }
    int p = j - H * K2;
    if (p < 5 * H) { pb[p] = bL[p] + bR[p]; return; }
    int q = p - 5 * H;
    if (q < H) { hb[q] = blh[q] + brh[q]; }
}

// ---------------- per-wave GEMM pass: acc[4][2] += A(64x512,LDS) @ Wg(256x512)^T ----------------
__device__ __forceinline__ void gemm_pass(const short* Abuf, const short* __restrict__ Wg,
                                          int colbase, int l15, int khalf, f32x4 acc[4][2]) {
#pragma unroll
    for (int mt = 0; mt < 4; ++mt) {
        acc[mt][0] = (f32x4){0.f, 0.f, 0.f, 0.f};
        acc[mt][1] = (f32x4){0.f, 0.f, 0.f, 0.f};
    }
#pragma unroll
    for (int kk = 0; kk < 16; ++kk) {
        int kel = kk * 32 + khalf * 8;        // bf16 element offset in K
        int kb = kel * 2;                     // byte offset
        short8 b0 = *(const short8*)(Wg + (colbase + l15) * K2 + kel);
        short8 b1 = *(const short8*)(Wg + (colbase + 16 + l15) * K2 + kel);
#pragma unroll
        for (int mt = 0; mt < 4; ++mt) {
            int row = mt * 16 + l15;
            short8 a = *(const short8*)((const char*)Abuf + swz(row, kb));
            acc[mt][0] = __builtin_amdgcn_mfma_f32_16x16x32_bf16(a, b0, acc[mt][0], 0, 0, 0);
            acc[mt][1] = __builtin_amdgcn_mfma_f32_16x16x32_bf16(a, b1, acc[mt][1], 0, 0, 0);
        }
    }
}

// ---------------- one tree level ----------------
__global__ __launch_bounds__(THREADS, 2) void level_kernel(
    const float* __restrict__ curIn, const int* __restrict__ tokens,
    const float* __restrict__ emb, float* __restrict__ curOut,
    const short* __restrict__ W1, const short* __restrict__ W2,
    const float* __restrict__ pb, const float* __restrict__ hb, int N) {
    __shared__ __align__(16) short A1[BM * K2];
    __shared__ __align__(16) short A2[BM * K2];
    const int tid = threadIdx.x;
    const int n0 = blockIdx.x * BM;

    // ---- staging: A1[n][0:256]=cur[2n], A1[n][256:512]=cur[2n+1]  (contiguous copy of 128 rows)
#pragma unroll
    for (int it = 0; it < 16; ++it) {
        int c = tid + it * THREADS;   // float4 chunk index in [0, 8192)
        int f = c * 4;                // flat float index in 128x256 region
        int r = f >> 8;               // local source row 0..127
        int col = f & 255;
        int gr = 2 * n0 + r;
        float4 v = make_float4(0.f, 0.f, 0.f, 0.f);
        if (gr < 2 * N) {
            const float* src = tokens ? (emb + (size_t)tokens[gr] * H) : (curIn + (size_t)gr * H);
            v = *(const float4*)(src + col);
        }
        int row = r >> 1;
        int k = ((r & 1) << 8) | col;
        S4 s; s.x = f2bf(v.x); s.y = f2bf(v.y); s.z = f2bf(v.z); s.w = f2bf(v.w);
        *(S4*)((char*)A1 + swz(row, k * 2)) = s;
    }
    __syncthreads();

    const int wave = tid >> 6, lane = tid & 63;
    const int l15 = lane & 15, khalf = lane >> 4;
    const int colbase = wave * 32;

    f32x4 acc[4][2];

    // ---- gates r_l (g=0), r_r (g=1): write A2 = r .* x  (bf16)
#pragma unroll
    for (int g = 0; g < 2; ++g) {
        gemm_pass(A1, W1 + g * H * K2, colbase, l15, khalf, acc);
#pragma unroll
        for (int nt = 0; nt < 2; ++nt) {
            int col = colbase + nt * 16 + l15;
            float bias = pb[g * H + col];
            int koff2 = (((g << 8) | col)) * 2;
#pragma unroll
            for (int mt = 0; mt < 4; ++mt) {
#pragma unroll
                for (int j = 0; j < 4; ++j) {
                    int row = mt * 16 + khalf * 4 + j;
                    float rg = sigm(acc[mt][nt][j] + bias);
                    float xv = bf2f(*(const short*)((const char*)A1 + swz(row, koff2)));
                    *(short*)((char*)A2 + swz(row, koff2)) = f2bf(rg * xv);
                }
            }
        }
    }
    __syncthreads();

    // ---- h_tilde = tanh(A2 @ W2^T + hb)
    float ht[4][2][4];
    gemm_pass(A2, W2, colbase, l15, khalf, acc);
#pragma unroll
    for (int nt = 0; nt < 2; ++nt) {
        int col = colbase + nt * 16 + l15;
        float bias = hb[col];
#pragma unroll
        for (int mt = 0; mt < 4; ++mt)
#pragma unroll
            for (int j = 0; j < 4; ++j)
                ht[mt][nt][j] = tanhf(acc[mt][nt][j] + bias);
    }

    // ---- z_l (g=2) * left + z_r (g=3) * right, fp32 operands from global
    float outv[4][2][4];
#pragma unroll
    for (int g = 2; g < 4; ++g) {
        gemm_pass(A1, W1 + g * H * K2, colbase, l15, khalf, acc);
#pragma unroll
        for (int nt = 0; nt < 2; ++nt) {
            int col = colbase + nt * 16 + l15;
            float bias = pb[g * H + col];
#pragma unroll
            for (int mt = 0; mt < 4; ++mt)
#pragma unroll
                for (int j = 0; j < 4; ++j) {
                    int rl = mt * 16 + khalf * 4 + j;
                    int gr = n0 + rl;
                    float z = sigm(acc[mt][nt][j] + bias);
                    float v = 0.f;
                    if (gr < N) {
                        int srow = 2 * gr + (g - 2);
                        v = tokens ? emb[(size_t)tokens[srow] * H + col]
                                   : curIn[(size_t)srow * H + col];
                    }
                    if (g == 2) outv[mt][nt][j] = z * v;
                    else        outv[mt][nt][j] += z * v;
                }
        }
    }

    // ---- z (g=4) * h_tilde, store
    gemm_pass(A1, W1 + 4 * H * K2, colbase, l15, khalf, acc);
#pragma unroll
    for (int nt = 0; nt < 2; ++nt) {
        int col = colbase + nt * 16 + l15;
        float bias = pb[4 * H + col];
#pragma unroll
        for (int mt = 0; mt < 4; ++mt)
#pragma unroll
            for (int j = 0; j < 4; ++j) {
                int rl = mt * 16 + khalf * 4 + j;
                int gr = n0 + rl;
                float z = sigm(acc[mt][nt][j] + bias);
                float o = outv[mt][nt][j] + z * ht[mt][nt][j];
                if (gr < N) curOut[(size_t)gr * H + col] = o;
            }
    }
}

// ---------------- finalize: out = (h,h,h) ----------------
__global__ void finalize_kernel(const float* __restrict__ h, float* __restrict__ out) {
    int i = threadIdx.x;
    if (i < 768) out[i] = h[i & 255];
}

extern "C" void kernel_launch(void* const* d_in, const int* in_sizes, int n_in,
                              void* d_out, int out_size, void* d_ws, size_t ws_size,
                              hipStream_t stream) {
    const int*   tokens = (const int*)d_in[0];
    const float* emb    = (const float*)d_in[1];
    const float* WL     = (const float*)d_in[2];
    const float* WR     = (const float*)d_in[3];
    const float* bL     = (const float*)d_in[4];
    const float* bR     = (const float*)d_in[5];
    const float* Wlh    = (const float*)d_in[6];
    const float* Wrh    = (const float*)d_in[7];
    const float* blh    = (const float*)d_in[8];
    const float* brh    = (const float*)d_in[9];

    char* ws = (char*)d_ws;
    short* W1 = (short*)ws;                        // 5*256*512 bf16 = 1310720 B
    short* W2 = W1 + 5 * H * K2;                   // 256*512 bf16  = 262144 B
    float* pb = (float*)(W2 + H * K2);             // 5*256 f32
    float* hb = pb + 5 * H;                        // 256 f32
    float* bufB = (float*)(ws + 2 * 1024 * 1024);          // 32768*256 f32 = 32 MB
    float* bufA = bufB + (size_t)32768 * H;                 // 16384*256 f32 = 16 MB

    // prep weights + biases
    {
        int total = 5 * H * K2 + H * K2 + 5 * H + H;
        int blocks = (total + 255) / 256;
        prep_kernel<<<blocks, 256, 0, stream>>>(WL, WR, Wlh, Wrh, bL, bR, blh, brh,
                                                W1, W2, pb, hb);
    }

    // 16 tree levels
    const float* in = nullptr;
    for (int l = 0; l < 16; ++l) {
        int N = 32768 >> l;
        float* out = (l & 1) ? bufA : bufB;
        int blocks = (N + BM - 1) / BM;
        level_kernel<<<blocks, THREADS, 0, stream>>>(
            in, (l == 0) ? tokens : nullptr, emb, out, W1, W2, pb, hb, N);
        in = out;
    }

    finalize_kernel<<<1, 768, 0, stream>>>(bufA, (float*)d_out);
}

// Round 2
// 1436.321 us; speedup vs baseline: 1.0423x; 1.0423x over previous
//
#include <hip/hip_runtime.h>
#include <hip/hip_bf16.h>

#define H 256
#define K2 512
#define BM 64
#define THREADS 512
#define HK2 (H * K2)

typedef __attribute__((ext_vector_type(8))) short short8;
typedef __attribute__((ext_vector_type(4))) float f32x4;

struct __align__(8) S4 { short x, y, z, w; };

__device__ __forceinline__ short f2bf(float f) {
    union { float f; unsigned u; } v; v.f = f;
    unsigned r = v.u + 0x7fffu + ((v.u >> 16) & 1u);
    return (short)(r >> 16);
}
__device__ __forceinline__ float bf2f(short s) {
    union { unsigned u; float f; } v; v.u = ((unsigned)(unsigned short)s) << 16;
    return v.f;
}
__device__ __forceinline__ float sigm(float x) {
    return 1.f / (1.f + __expf(-x));
}
__device__ __forceinline__ float tanh_f(float x) {
    float e = __expf(2.f * x);
    return 1.f - 2.f / (e + 1.f);
}
__device__ __forceinline__ int swz(int row, int kbytes) {
    return ((row << 10) + kbytes) ^ ((row & 7) << 4);
}

// ---------------- weight/bias prep ----------------
__global__ void prep_kernel(const float* __restrict__ WL, const float* __restrict__ WR,
                            const float* __restrict__ Wlh, const float* __restrict__ Wrh,
                            const float* __restrict__ bL, const float* __restrict__ bR,
                            const float* __restrict__ blh, const float* __restrict__ brh,
                            short* __restrict__ W1, short* __restrict__ W2,
                            float* __restrict__ pb, float* __restrict__ hb) {
    int i = blockIdx.x * blockDim.x + threadIdx.x;
    const int nW1 = 5 * HK2;
    if (i < nW1) {
        int g = i / HK2;
        int rem = i % HK2;
        int o = rem / K2, k = rem % K2;
        float v = (k < H) ? WL[(g * H + o) * H + k] : WR[(g * H + o) * H + (k - H)];
        W1[i] = f2bf(v);
        return;
    }
    int j = i - nW1;
    if (j < HK2) {
        int o = j / K2, k = j % K2;
        float v = (k < H) ? Wlh[o * H + k] : Wrh[o * H + (k - H)];
        W2[j] = f2bf(v);
        return;
    }
    int p = j - HK2;
    if (p < 5 * H) { pb[p] = bL[p] + bR[p]; return; }
    int q = p - 5 * H;
    if (q < H) { hb[q] = blh[q] + brh[q]; }
}

// ---------------- one 64-pair tile of one level ----------------
__device__ __forceinline__ void do_level(const float* __restrict__ curIn,
                                         const int* __restrict__ tokens,
                                         const float* __restrict__ emb,
                                         float* __restrict__ curOut,
                                         const short* __restrict__ W1,
                                         const short* __restrict__ W2,
                                         const float* __restrict__ pb,
                                         const float* __restrict__ hb,
                                         int N, int n0, short* A1, short* A2) {
    const int tid = threadIdx.x;
    __syncthreads();  // protect LDS reuse across calls (tail kernel)

    // ---- staging: A1[n][0:256]=row 2n, A1[n][256:512]=row 2n+1, swizzled bf16
#pragma unroll
    for (int it = 0; it < 16; ++it) {
        int c = tid + it * THREADS;       // float4 chunk in [0, 8192)
        int r = c >> 6;                   // source row 0..127
        int col = (c & 63) << 2;
        int gr = 2 * n0 + r;
        float4 v = make_float4(0.f, 0.f, 0.f, 0.f);
        if (gr < 2 * N) {
            const float* src = tokens ? (emb + (size_t)tokens[gr] * H)
                                      : (curIn + (size_t)gr * H);
            v = *(const float4*)(src + col);
        }
        int row = r >> 1;
        int kel = ((r & 1) << 8) | col;
        S4 s; s.x = f2bf(v.x); s.y = f2bf(v.y); s.z = f2bf(v.z); s.w = f2bf(v.w);
        *(S4*)((char*)A1 + swz(row, kel * 2)) = s;
    }
    __syncthreads();

    const int wave = tid >> 6, lane = tid & 63;
    const int l15 = lane & 15, khalf = lane >> 4;
    const int col0 = wave * 32;

    // ================= P1: gates r_l (g=0), r_r (g=1), one A1 stream =================
    f32x4 acc1[2][4][2];
#pragma unroll
    for (int g = 0; g < 2; ++g)
#pragma unroll
        for (int rt = 0; rt < 4; ++rt)
#pragma unroll
            for (int ct = 0; ct < 2; ++ct)
                acc1[g][rt][ct] = (f32x4){0.f, 0.f, 0.f, 0.f};

    const short* b1p[2][2];
#pragma unroll
    for (int g = 0; g < 2; ++g)
#pragma unroll
        for (int ct = 0; ct < 2; ++ct)
            b1p[g][ct] = W1 + g * HK2 + (size_t)(col0 + ct * 16 + l15) * K2 + khalf * 8;

#pragma unroll
    for (int kk = 0; kk < 16; ++kk) {
        short8 a[4];
#pragma unroll
        for (int rt = 0; rt < 4; ++rt)
            a[rt] = *(const short8*)((const char*)A1 + swz(rt * 16 + l15, kk * 64 + khalf * 16));
        short8 b[2][2];
#pragma unroll
        for (int g = 0; g < 2; ++g)
#pragma unroll
            for (int ct = 0; ct < 2; ++ct)
                b[g][ct] = *(const short8*)(b1p[g][ct] + kk * 32);
#pragma unroll
        for (int g = 0; g < 2; ++g)
#pragma unroll
            for (int rt = 0; rt < 4; ++rt)
#pragma unroll
                for (int ct = 0; ct < 2; ++ct)
                    acc1[g][rt][ct] = __builtin_amdgcn_mfma_f32_16x16x32_bf16(
                        a[rt], b[g][ct], acc1[g][rt][ct], 0, 0, 0);
    }

    // epilogue: A2 = sigmoid(pre) .* x  (bf16, swizzled)
#pragma unroll
    for (int g = 0; g < 2; ++g)
#pragma unroll
        for (int ct = 0; ct < 2; ++ct) {
            int col = col0 + ct * 16 + l15;
            float bias = pb[g * H + col];
            int koff2 = ((g << 8) | col) * 2;
#pragma unroll
            for (int rt = 0; rt < 4; ++rt)
#pragma unroll
                for (int j = 0; j < 4; ++j) {
                    int row = rt * 16 + khalf * 4 + j;
                    float rg = sigm(acc1[g][rt][ct][j] + bias);
                    float xv = bf2f(*(const short*)((const char*)A1 + swz(row, koff2)));
                    *(short*)((char*)A2 + swz(row, koff2)) = f2bf(rg * xv);
                }
        }
    __syncthreads();

    // ================= P2: h_tilde = tanh(A2 @ W2^T + hb) =================
    f32x4 acc2[4][2];
#pragma unroll
    for (int rt = 0; rt < 4; ++rt)
#pragma unroll
        for (int ct = 0; ct < 2; ++ct)
            acc2[rt][ct] = (f32x4){0.f, 0.f, 0.f, 0.f};

    const short* b2p[2];
#pragma unroll
    for (int ct = 0; ct < 2; ++ct)
        b2p[ct] = W2 + (size_t)(col0 + ct * 16 + l15) * K2 + khalf * 8;

#pragma unroll
    for (int kk = 0; kk < 16; ++kk) {
        short8 a[4];
#pragma unroll
        for (int rt = 0; rt < 4; ++rt)
            a[rt] = *(const short8*)((const char*)A2 + swz(rt * 16 + l15, kk * 64 + khalf * 16));
        short8 b[2];
#pragma unroll
        for (int ct = 0; ct < 2; ++ct)
            b[ct] = *(const short8*)(b2p[ct] + kk * 32);
#pragma unroll
        for (int rt = 0; rt < 4; ++rt)
#pragma unroll
            for (int ct = 0; ct < 2; ++ct)
                acc2[rt][ct] = __builtin_amdgcn_mfma_f32_16x16x32_bf16(
                    a[rt], b[ct], acc2[rt][ct], 0, 0, 0);
    }

    float ht[4][2][4];
#pragma unroll
    for (int ct = 0; ct < 2; ++ct) {
        int col = col0 + ct * 16 + l15;
        float bias = hb[col];
#pragma unroll
        for (int rt = 0; rt < 4; ++rt)
#pragma unroll
            for (int j = 0; j < 4; ++j)
                ht[rt][ct][j] = tanh_f(acc2[rt][ct][j] + bias);
    }

    // ================= P3: gates z_l, z_r, z in one A1 stream =================
    f32x4 acc3[3][4][2];
#pragma unroll
    for (int g = 0; g < 3; ++g)
#pragma unroll
        for (int rt = 0; rt < 4; ++rt)
#pragma unroll
            for (int ct = 0; ct < 2; ++ct)
                acc3[g][rt][ct] = (f32x4){0.f, 0.f, 0.f, 0.f};

    const short* b3p[3][2];
#pragma unroll
    for (int g = 0; g < 3; ++g)
#pragma unroll
        for (int ct = 0; ct < 2; ++ct)
            b3p[g][ct] = W1 + (g + 2) * HK2 + (size_t)(col0 + ct * 16 + l15) * K2 + khalf * 8;

#pragma unroll
    for (int kk = 0; kk < 16; ++kk) {
        short8 a[4];
#pragma unroll
        for (int rt = 0; rt < 4; ++rt)
            a[rt] = *(const short8*)((const char*)A1 + swz(rt * 16 + l15, kk * 64 + khalf * 16));
        short8 b[3][2];
#pragma unroll
        for (int g = 0; g < 3; ++g)
#pragma unroll
            for (int ct = 0; ct < 2; ++ct)
                b[g][ct] = *(const short8*)(b3p[g][ct] + kk * 32);
#pragma unroll
        for (int g = 0; g < 3; ++g)
#pragma unroll
            for (int rt = 0; rt < 4; ++rt)
#pragma unroll
                for (int ct = 0; ct < 2; ++ct)
                    acc3[g][rt][ct] = __builtin_amdgcn_mfma_f32_16x16x32_bf16(
                        a[rt], b[g][ct], acc3[g][rt][ct], 0, 0, 0);
    }

    // epilogue: out = z_l.*left + z_r.*right + z.*h_tilde  (x from A1 bf16)
#pragma unroll
    for (int ct = 0; ct < 2; ++ct) {
        int col = col0 + ct * 16 + l15;
        float bzl = pb[2 * H + col];
        float bzr = pb[3 * H + col];
        float bzz = pb[4 * H + col];
#pragma unroll
        for (int rt = 0; rt < 4; ++rt)
#pragma unroll
            for (int j = 0; j < 4; ++j) {
                int row = rt * 16 + khalf * 4 + j;
                int gr = n0 + row;
                if (gr < N) {
                    float zl = sigm(acc3[0][rt][ct][j] + bzl);
                    float zr = sigm(acc3[1][rt][ct][j] + bzr);
                    float zz = sigm(acc3[2][rt][ct][j] + bzz);
                    float xl = bf2f(*(const short*)((const char*)A1 + swz(row, col * 2)));
                    float xr = bf2f(*(const short*)((const char*)A1 + swz(row, (col + 256) * 2)));
                    curOut[(size_t)gr * H + col] = zl * xl + zr * xr + zz * ht[rt][ct][j];
                }
            }
    }
}

// ---------------- main per-level kernel ----------------
__global__ __launch_bounds__(THREADS, 2) void level_kernel(
    const float* __restrict__ curIn, const int* __restrict__ tokens,
    const float* __restrict__ emb, float* __restrict__ curOut,
    const short* __restrict__ W1, const short* __restrict__ W2,
    const float* __restrict__ pb, const float* __restrict__ hb, int N) {
    __shared__ __align__(16) short A1[BM * K2];
    __shared__ __align__(16) short A2[BM * K2];
    do_level(curIn, tokens, emb, curOut, W1, W2, pb, hb, N, blockIdx.x * BM, A1, A2);
}

// ---------------- fused tail: levels 9..15 + finalize ----------------
__global__ __launch_bounds__(THREADS, 2) void tail_kernel(
    float* bufA, float* bufB,
    const short* __restrict__ W1, const short* __restrict__ W2,
    const float* __restrict__ pb, const float* __restrict__ hb,
    float* __restrict__ out) {
    __shared__ __align__(16) short A1[BM * K2];
    __shared__ __align__(16) short A2[BM * K2];
    for (int l = 9; l <= 15; ++l) {
        int N = 32768 >> l;
        const float* in = (l & 1) ? bufB : bufA;
        float* o = (l & 1) ? bufA : bufB;
        do_level(in, nullptr, nullptr, o, W1, W2, pb, hb, N, 0, A1, A2);
        __threadfence_block();
    }
    __syncthreads();
    for (int i = threadIdx.x; i < 768; i += THREADS)
        out[i] = bufA[i & 255];   // h = bufA row 0 (level 15 writes bufA)
}

extern "C" void kernel_launch(void* const* d_in, const int* in_sizes, int n_in,
                              void* d_out, int out_size, void* d_ws, size_t ws_size,
                              hipStream_t stream) {
    const int*   tokens = (const int*)d_in[0];
    const float* emb    = (const float*)d_in[1];
    const float* WL     = (const float*)d_in[2];
    const float* WR     = (const float*)d_in[3];
    const float* bL     = (const float*)d_in[4];
    const float* bR     = (const float*)d_in[5];
    const float* Wlh    = (const float*)d_in[6];
    const float* Wrh    = (const float*)d_in[7];
    const float* blh    = (const float*)d_in[8];
    const float* brh    = (const float*)d_in[9];

    char* ws = (char*)d_ws;
    short* W1 = (short*)ws;                    // 5*256*512 bf16
    short* W2 = W1 + 5 * HK2;                  // 256*512 bf16
    float* pb = (float*)(W2 + HK2);            // 5*256 f32
    float* hb = pb + 5 * H;                    // 256 f32
    float* bufB = (float*)(ws + 2 * 1024 * 1024);   // 32768*256 f32
    float* bufA = bufB + (size_t)32768 * H;         // 16384*256 f32

    {
        int total = 5 * HK2 + HK2 + 5 * H + H;
        int blocks = (total + 255) / 256;
        prep_kernel<<<blocks, 256, 0, stream>>>(WL, WR, Wlh, Wrh, bL, bR, blh, brh,
                                                W1, W2, pb, hb);
    }

    // levels 0..8 as separate launches
    const float* in = nullptr;
    for (int l = 0; l <= 8; ++l) {
        int N = 32768 >> l;
        float* out = (l & 1) ? bufA : bufB;
        int blocks = (N + BM - 1) / BM;
        level_kernel<<<blocks, THREADS, 0, stream>>>(
            in, (l == 0) ? tokens : nullptr, emb, out, W1, W2, pb, hb, N);
        in = out;
    }

    // levels 9..15 + finalize in one block
    tail_kernel<<<1, THREADS, 0, stream>>>(bufA, bufB, W1, W2, pb, hb, (float*)d_out);
}

// Round 4
// 1271.794 us; speedup vs baseline: 1.1772x; 1.1294x over previous
//
#include <hip/hip_runtime.h>
#include <hip/hip_bf16.h>

#define H 256
#define K2 512
#define BM 64
#define THREADS 512
#define HK2 (H * K2)

typedef __attribute__((ext_vector_type(8))) short short8;
typedef __attribute__((ext_vector_type(4))) float f32x4;

struct __align__(8) S4 { short x, y, z, w; };

__device__ __forceinline__ short f2bf(float f) {
    union { float f; unsigned u; } v; v.f = f;
    unsigned r = v.u + 0x7fffu + ((v.u >> 16) & 1u);
    return (short)(r >> 16);
}
__device__ __forceinline__ float bf2f(short s) {
    union { unsigned u; float f; } v; v.u = ((unsigned)(unsigned short)s) << 16;
    return v.f;
}
__device__ __forceinline__ float sigm(float x) {
    return 1.f / (1.f + __expf(-x));
}
__device__ __forceinline__ float tanh_f(float x) {
    float e = __expf(2.f * x);
    return 1.f - 2.f / (e + 1.f);
}
__device__ __forceinline__ int swz(int row, int kbytes) {
    return ((row << 10) + kbytes) ^ ((row & 7) << 4);
}

// ---------------- weight/bias prep ----------------
__global__ void prep_kernel(const float* __restrict__ WL, const float* __restrict__ WR,
                            const float* __restrict__ Wlh, const float* __restrict__ Wrh,
                            const float* __restrict__ bL, const float* __restrict__ bR,
                            const float* __restrict__ blh, const float* __restrict__ brh,
                            short* __restrict__ W1, short* __restrict__ W2,
                            float* __restrict__ pb, float* __restrict__ hb) {
    int i = blockIdx.x * blockDim.x + threadIdx.x;
    const int nW1 = 5 * HK2;
    if (i < nW1) {
        int g = i / HK2;
        int rem = i % HK2;
        int o = rem / K2, k = rem % K2;
        float v = (k < H) ? WL[(g * H + o) * H + k] : WR[(g * H + o) * H + (k - H)];
        W1[i] = f2bf(v);
        return;
    }
    int j = i - nW1;
    if (j < HK2) {
        int o = j / K2, k = j % K2;
        float v = (k < H) ? Wlh[o * H + k] : Wrh[o * H + (k - H)];
        W2[j] = f2bf(v);
        return;
    }
    int p = j - HK2;
    if (p < 5 * H) { pb[p] = bL[p] + bR[p]; return; }
    int q = p - 5 * H;
    if (q < H) { hb[q] = blh[q] + brh[q]; }
}

// ---------------- per-level kernel (one 64-pair tile per block) ----------------
__global__ __launch_bounds__(THREADS, 1) void level_kernel(
    const float* __restrict__ curIn, const int* __restrict__ tokens,
    const float* __restrict__ emb, float* __restrict__ curOut,
    const short* __restrict__ W1, const short* __restrict__ W2,
    const float* __restrict__ pb, const float* __restrict__ hb, int N) {
    __shared__ __align__(16) short A1[BM * K2];
    __shared__ __align__(16) short A2[BM * K2];
    const int tid = threadIdx.x;
    const int n0 = blockIdx.x * BM;

    // ---- staging: A1[n][0:256]=row 2n, A1[n][256:512]=row 2n+1, swizzled bf16
#pragma unroll
    for (int it = 0; it < 16; ++it) {
        int c = tid + it * THREADS;       // float4 chunk in [0, 8192)
        int r = c >> 6;                   // source row 0..127
        int col = (c & 63) << 2;
        int gr = 2 * n0 + r;
        float4 v = make_float4(0.f, 0.f, 0.f, 0.f);
        if (gr < 2 * N) {
            const float* src = tokens ? (emb + (size_t)tokens[gr] * H)
                                      : (curIn + (size_t)gr * H);
            v = *(const float4*)(src + col);
        }
        int row = r >> 1;
        int kel = ((r & 1) << 8) | col;
        S4 s; s.x = f2bf(v.x); s.y = f2bf(v.y); s.z = f2bf(v.z); s.w = f2bf(v.w);
        *(S4*)((char*)A1 + swz(row, kel * 2)) = s;
    }
    __syncthreads();

    const int wave = tid >> 6, lane = tid & 63;
    const int l15 = lane & 15, khalf = lane >> 4;
    const int col0 = wave * 32;

    // ================= P1: gates r_l (g=0), r_r (g=1), one A1 stream =================
    f32x4 acc1[2][4][2];
#pragma unroll
    for (int g = 0; g < 2; ++g)
#pragma unroll
        for (int rt = 0; rt < 4; ++rt)
#pragma unroll
            for (int ct = 0; ct < 2; ++ct)
                acc1[g][rt][ct] = (f32x4){0.f, 0.f, 0.f, 0.f};

    const short* b1p[2][2];
#pragma unroll
    for (int g = 0; g < 2; ++g)
#pragma unroll
        for (int ct = 0; ct < 2; ++ct)
            b1p[g][ct] = W1 + g * HK2 + (size_t)(col0 + ct * 16 + l15) * K2 + khalf * 8;

#pragma unroll
    for (int kk = 0; kk < 16; ++kk) {
        short8 a[4];
#pragma unroll
        for (int rt = 0; rt < 4; ++rt)
            a[rt] = *(const short8*)((const char*)A1 + swz(rt * 16 + l15, kk * 64 + khalf * 16));
        short8 b[2][2];
#pragma unroll
        for (int g = 0; g < 2; ++g)
#pragma unroll
            for (int ct = 0; ct < 2; ++ct)
                b[g][ct] = *(const short8*)(b1p[g][ct] + kk * 32);
#pragma unroll
        for (int g = 0; g < 2; ++g)
#pragma unroll
            for (int rt = 0; rt < 4; ++rt)
#pragma unroll
                for (int ct = 0; ct < 2; ++ct)
                    acc1[g][rt][ct] = __builtin_amdgcn_mfma_f32_16x16x32_bf16(
                        a[rt], b[g][ct], acc1[g][rt][ct], 0, 0, 0);
    }

    // epilogue: A2 = sigmoid(pre) .* x  (bf16, swizzled)
#pragma unroll
    for (int g = 0; g < 2; ++g)
#pragma unroll
        for (int ct = 0; ct < 2; ++ct) {
            int col = col0 + ct * 16 + l15;
            float bias = pb[g * H + col];
            int koff2 = ((g << 8) | col) * 2;
#pragma unroll
            for (int rt = 0; rt < 4; ++rt)
#pragma unroll
                for (int j = 0; j < 4; ++j) {
                    int row = rt * 16 + khalf * 4 + j;
                    float rg = sigm(acc1[g][rt][ct][j] + bias);
                    float xv = bf2f(*(const short*)((const char*)A1 + swz(row, koff2)));
                    *(short*)((char*)A2 + swz(row, koff2)) = f2bf(rg * xv);
                }
        }
    __syncthreads();

    // ================= P2: h_tilde = tanh(A2 @ W2^T + hb) =================
    f32x4 acc2[4][2];
#pragma unroll
    for (int rt = 0; rt < 4; ++rt)
#pragma unroll
        for (int ct = 0; ct < 2; ++ct)
            acc2[rt][ct] = (f32x4){0.f, 0.f, 0.f, 0.f};

    const short* b2p[2];
#pragma unroll
    for (int ct = 0; ct < 2; ++ct)
        b2p[ct] = W2 + (size_t)(col0 + ct * 16 + l15) * K2 + khalf * 8;

#pragma unroll
    for (int kk = 0; kk < 16; ++kk) {
        short8 a[4];
#pragma unroll
        for (int rt = 0; rt < 4; ++rt)
            a[rt] = *(const short8*)((const char*)A2 + swz(rt * 16 + l15, kk * 64 + khalf * 16));
        short8 b[2];
#pragma unroll
        for (int ct = 0; ct < 2; ++ct)
            b[ct] = *(const short8*)(b2p[ct] + kk * 32);
#pragma unroll
        for (int rt = 0; rt < 4; ++rt)
#pragma unroll
            for (int ct = 0; ct < 2; ++ct)
                acc2[rt][ct] = __builtin_amdgcn_mfma_f32_16x16x32_bf16(
                    a[rt], b[ct], acc2[rt][ct], 0, 0, 0);
    }

    float ht[4][2][4];
#pragma unroll
    for (int ct = 0; ct < 2; ++ct) {
        int col = col0 + ct * 16 + l15;
        float bias = hb[col];
#pragma unroll
        for (int rt = 0; rt < 4; ++rt)
#pragma unroll
            for (int j = 0; j < 4; ++j)
                ht[rt][ct][j] = tanh_f(acc2[rt][ct][j] + bias);
    }

    // ================= P3: gates z_l, z_r, z in one A1 stream =================
    f32x4 acc3[3][4][2];
#pragma unroll
    for (int g = 0; g < 3; ++g)
#pragma unroll
        for (int rt = 0; rt < 4; ++rt)
#pragma unroll
            for (int ct = 0; ct < 2; ++ct)
                acc3[g][rt][ct] = (f32x4){0.f, 0.f, 0.f, 0.f};

    const short* b3p[3][2];
#pragma unroll
    for (int g = 0; g < 3; ++g)
#pragma unroll
        for (int ct = 0; ct < 2; ++ct)
            b3p[g][ct] = W1 + (g + 2) * HK2 + (size_t)(col0 + ct * 16 + l15) * K2 + khalf * 8;

#pragma unroll
    for (int kk = 0; kk < 16; ++kk) {
        short8 a[4];
#pragma unroll
        for (int rt = 0; rt < 4; ++rt)
            a[rt] = *(const short8*)((const char*)A1 + swz(rt * 16 + l15, kk * 64 + khalf * 16));
        short8 b[3][2];
#pragma unroll
        for (int g = 0; g < 3; ++g)
#pragma unroll
            for (int ct = 0; ct < 2; ++ct)
                b[g][ct] = *(const short8*)(b3p[g][ct] + kk * 32);
#pragma unroll
        for (int g = 0; g < 3; ++g)
#pragma unroll
            for (int rt = 0; rt < 4; ++rt)
#pragma unroll
                for (int ct = 0; ct < 2; ++ct)
                    acc3[g][rt][ct] = __builtin_amdgcn_mfma_f32_16x16x32_bf16(
                        a[rt], b[g][ct], acc3[g][rt][ct], 0, 0, 0);
    }

    // epilogue: out = z_l.*left + z_r.*right + z.*h_tilde  (x from A1 bf16)
#pragma unroll
    for (int ct = 0; ct < 2; ++ct) {
        int col = col0 + ct * 16 + l15;
        float bzl = pb[2 * H + col];
        float bzr = pb[3 * H + col];
        float bzz = pb[4 * H + col];
#pragma unroll
        for (int rt = 0; rt < 4; ++rt)
#pragma unroll
            for (int j = 0; j < 4; ++j) {
                int row = rt * 16 + khalf * 4 + j;
                int gr = n0 + row;
                if (gr < N) {
                    float zl = sigm(acc3[0][rt][ct][j] + bzl);
                    float zr = sigm(acc3[1][rt][ct][j] + bzr);
                    float zz = sigm(acc3[2][rt][ct][j] + bzz);
                    float xl = bf2f(*(const short*)((const char*)A1 + swz(row, col * 2)));
                    float xr = bf2f(*(const short*)((const char*)A1 + swz(row, (col + 256) * 2)));
                    curOut[(size_t)gr * H + col] = zl * xl + zr * xr + zz * ht[rt][ct][j];
                }
            }
    }
}

// ---------------- finalize: out = (h,h,h) ----------------
__global__ void finalize_kernel(const float* __restrict__ h, float* __restrict__ out) {
    int i = threadIdx.x;
    if (i < 768) out[i] = h[i & 255];
}

extern "C" void kernel_launch(void* const* d_in, const int* in_sizes, int n_in,
                              void* d_out, int out_size, void* d_ws, size_t ws_size,
                              hipStream_t stream) {
    const int*   tokens = (const int*)d_in[0];
    const float* emb    = (const float*)d_in[1];
    const float* WL     = (const float*)d_in[2];
    const float* WR     = (const float*)d_in[3];
    const float* bL     = (const float*)d_in[4];
    const float* bR     = (const float*)d_in[5];
    const float* Wlh    = (const float*)d_in[6];
    const float* Wrh    = (const float*)d_in[7];
    const float* blh    = (const float*)d_in[8];
    const float* brh    = (const float*)d_in[9];

    char* ws = (char*)d_ws;
    short* W1 = (short*)ws;                    // 5*256*512 bf16
    short* W2 = W1 + 5 * HK2;                  // 256*512 bf16
    float* pb = (float*)(W2 + HK2);            // 5*256 f32
    float* hb = pb + 5 * H;                    // 256 f32
    float* bufB = (float*)(ws + 2 * 1024 * 1024);   // 32768*256 f32
    float* bufA = bufB + (size_t)32768 * H;         // 16384*256 f32

    {
        int total = 5 * HK2 + HK2 + 5 * H + H;
        int blocks = (total + 255) / 256;
        prep_kernel<<<blocks, 256, 0, stream>>>(WL, WR, Wlh, Wrh, bL, bR, blh, brh,
                                                W1, W2, pb, hb);
    }

    // all 16 levels as separate launches
    const float* in = nullptr;
    for (int l = 0; l < 16; ++l) {
        int N = 32768 >> l;
        float* out = (l & 1) ? bufA : bufB;
        int blocks = (N + BM - 1) / BM;
        level_kernel<<<blocks, THREADS, 0, stream>>>(
            in, (l == 0) ? tokens : nullptr, emb, out, W1, W2, pb, hb, N);
        in = out;
    }

    finalize_kernel<<<1, 768, 0, stream>>>(bufA, (float*)d_out);
}

// Round 6
// 1242.193 us; speedup vs baseline: 1.2052x; 1.0238x over previous
//
#include <hip/hip_runtime.h>
#include <hip/hip_bf16.h>

#define H 256
#define K2 512
#define BM 32
#define THREADS 512
#define HK2 (H * K2)

typedef __attribute__((ext_vector_type(8))) short short8;
typedef __attribute__((ext_vector_type(4))) float f32x4;

struct __align__(8) S4 { short x, y, z, w; };

__device__ __forceinline__ short f2bf(float f) {
    union { float f; unsigned u; } v; v.f = f;
    unsigned r = v.u + 0x7fffu + ((v.u >> 16) & 1u);
    return (short)(r >> 16);
}
__device__ __forceinline__ float bf2f(short s) {
    union { unsigned u; float f; } v; v.u = ((unsigned)(unsigned short)s) << 16;
    return v.f;
}
__device__ __forceinline__ float sigm(float x) {
    return 1.f / (1.f + __expf(-x));
}
__device__ __forceinline__ float tanh_f(float x) {
    float e = __expf(2.f * x);
    return 1.f - 2.f / (e + 1.f);
}
__device__ __forceinline__ int swz(int row, int kbytes) {
    return ((row << 10) + kbytes) ^ ((row & 7) << 4);
}

// ---------------- weight/bias prep ----------------
__global__ void prep_kernel(const float* __restrict__ WL, const float* __restrict__ WR,
                            const float* __restrict__ Wlh, const float* __restrict__ Wrh,
                            const float* __restrict__ bL, const float* __restrict__ bR,
                            const float* __restrict__ blh, const float* __restrict__ brh,
                            short* __restrict__ W1, short* __restrict__ W2,
                            float* __restrict__ pb, float* __restrict__ hb) {
    int i = blockIdx.x * blockDim.x + threadIdx.x;
    const int nW1 = 5 * HK2;
    if (i < nW1) {
        int g = i / HK2;
        int rem = i % HK2;
        int o = rem / K2, k = rem % K2;
        float v = (k < H) ? WL[(g * H + o) * H + k] : WR[(g * H + o) * H + (k - H)];
        W1[i] = f2bf(v);
        return;
    }
    int j = i - nW1;
    if (j < HK2) {
        int o = j / K2, k = j % K2;
        float v = (k < H) ? Wlh[o * H + k] : Wrh[o * H + (k - H)];
        W2[j] = f2bf(v);
        return;
    }
    int p = j - HK2;
    if (p < 5 * H) { pb[p] = bL[p] + bR[p]; return; }
    int q = p - 5 * H;
    if (q < H) { hb[q] = blh[q] + brh[q]; }
}

// ---------------- per-level kernel (one 32-pair tile per block) ----------------
__global__ __launch_bounds__(THREADS, 2) void level_kernel(
    const float* __restrict__ curIn, const int* __restrict__ tokens,
    const float* __restrict__ emb, float* __restrict__ curOut,
    const short* __restrict__ W1, const short* __restrict__ W2,
    const float* __restrict__ pb, const float* __restrict__ hb, int N) {
    __shared__ __align__(16) short A1[BM * K2];   // 32 KB
    __shared__ __align__(16) short A2[BM * K2];   // 32 KB
    const int tid = threadIdx.x;
    const int n0 = blockIdx.x * BM;

    // ---- staging: A1[n][0:256]=row 2n, A1[n][256:512]=row 2n+1, swizzled bf16
#pragma unroll
    for (int it = 0; it < 8; ++it) {
        int c = tid + it * THREADS;       // float4 chunk in [0, 4096)
        int r = c >> 6;                   // source row 0..63
        int col = (c & 63) << 2;
        int gr = 2 * n0 + r;
        float4 v = make_float4(0.f, 0.f, 0.f, 0.f);
        if (gr < 2 * N) {
            const float* src = tokens ? (emb + (size_t)tokens[gr] * H)
                                      : (curIn + (size_t)gr * H);
            v = *(const float4*)(src + col);
        }
        int row = r >> 1;
        int kel = ((r & 1) << 8) | col;
        S4 s; s.x = f2bf(v.x); s.y = f2bf(v.y); s.z = f2bf(v.z); s.w = f2bf(v.w);
        *(S4*)((char*)A1 + swz(row, kel * 2)) = s;
    }
    __syncthreads();

    const int wave = tid >> 6, lane = tid & 63;
    const int l15 = lane & 15, khalf = lane >> 4;
    const int col0 = wave * 32;

    // ================= P1: gates r_l (g=0), r_r (g=1), one A1 stream =================
    f32x4 acc1[2][2][2];
#pragma unroll
    for (int g = 0; g < 2; ++g)
#pragma unroll
        for (int rt = 0; rt < 2; ++rt)
#pragma unroll
            for (int ct = 0; ct < 2; ++ct)
                acc1[g][rt][ct] = (f32x4){0.f, 0.f, 0.f, 0.f};

    const short* b1p[2][2];
#pragma unroll
    for (int g = 0; g < 2; ++g)
#pragma unroll
        for (int ct = 0; ct < 2; ++ct)
            b1p[g][ct] = W1 + g * HK2 + (size_t)(col0 + ct * 16 + l15) * K2 + khalf * 8;

#pragma unroll
    for (int kk = 0; kk < 16; ++kk) {
        short8 a[2];
#pragma unroll
        for (int rt = 0; rt < 2; ++rt)
            a[rt] = *(const short8*)((const char*)A1 + swz(rt * 16 + l15, kk * 64 + khalf * 16));
        short8 b[2][2];
#pragma unroll
        for (int g = 0; g < 2; ++g)
#pragma unroll
            for (int ct = 0; ct < 2; ++ct)
                b[g][ct] = *(const short8*)(b1p[g][ct] + kk * 32);
#pragma unroll
        for (int g = 0; g < 2; ++g)
#pragma unroll
            for (int rt = 0; rt < 2; ++rt)
#pragma unroll
                for (int ct = 0; ct < 2; ++ct)
                    acc1[g][rt][ct] = __builtin_amdgcn_mfma_f32_16x16x32_bf16(
                        a[rt], b[g][ct], acc1[g][rt][ct], 0, 0, 0);
    }

    // epilogue: A2 = sigmoid(pre) .* x  (bf16, swizzled)
#pragma unroll
    for (int g = 0; g < 2; ++g)
#pragma unroll
        for (int ct = 0; ct < 2; ++ct) {
            int col = col0 + ct * 16 + l15;
            float bias = pb[g * H + col];
            int koff2 = ((g << 8) | col) * 2;
#pragma unroll
            for (int rt = 0; rt < 2; ++rt)
#pragma unroll
                for (int j = 0; j < 4; ++j) {
                    int row = rt * 16 + khalf * 4 + j;
                    float rg = sigm(acc1[g][rt][ct][j] + bias);
                    float xv = bf2f(*(const short*)((const char*)A1 + swz(row, koff2)));
                    *(short*)((char*)A2 + swz(row, koff2)) = f2bf(rg * xv);
                }
        }
    __syncthreads();

    // ================= P2: h_tilde = tanh(A2 @ W2^T + hb) =================
    f32x4 acc2[2][2];
#pragma unroll
    for (int rt = 0; rt < 2; ++rt)
#pragma unroll
        for (int ct = 0; ct < 2; ++ct)
            acc2[rt][ct] = (f32x4){0.f, 0.f, 0.f, 0.f};

    const short* b2p[2];
#pragma unroll
    for (int ct = 0; ct < 2; ++ct)
        b2p[ct] = W2 + (size_t)(col0 + ct * 16 + l15) * K2 + khalf * 8;

#pragma unroll
    for (int kk = 0; kk < 16; ++kk) {
        short8 a[2];
#pragma unroll
        for (int rt = 0; rt < 2; ++rt)
            a[rt] = *(const short8*)((const char*)A2 + swz(rt * 16 + l15, kk * 64 + khalf * 16));
        short8 b[2];
#pragma unroll
        for (int ct = 0; ct < 2; ++ct)
            b[ct] = *(const short8*)(b2p[ct] + kk * 32);
#pragma unroll
        for (int rt = 0; rt < 2; ++rt)
#pragma unroll
            for (int ct = 0; ct < 2; ++ct)
                acc2[rt][ct] = __builtin_amdgcn_mfma_f32_16x16x32_bf16(
                    a[rt], b[ct], acc2[rt][ct], 0, 0, 0);
    }

    float ht[2][2][4];
#pragma unroll
    for (int ct = 0; ct < 2; ++ct) {
        int col = col0 + ct * 16 + l15;
        float bias = hb[col];
#pragma unroll
        for (int rt = 0; rt < 2; ++rt)
#pragma unroll
            for (int j = 0; j < 4; ++j)
                ht[rt][ct][j] = tanh_f(acc2[rt][ct][j] + bias);
    }

    // ================= P3: gates z_l, z_r, z in one A1 stream =================
    f32x4 acc3[3][2][2];
#pragma unroll
    for (int g = 0; g < 3; ++g)
#pragma unroll
        for (int rt = 0; rt < 2; ++rt)
#pragma unroll
            for (int ct = 0; ct < 2; ++ct)
                acc3[g][rt][ct] = (f32x4){0.f, 0.f, 0.f, 0.f};

    const short* b3p[3][2];
#pragma unroll
    for (int g = 0; g < 3; ++g)
#pragma unroll
        for (int ct = 0; ct < 2; ++ct)
            b3p[g][ct] = W1 + (g + 2) * HK2 + (size_t)(col0 + ct * 16 + l15) * K2 + khalf * 8;

#pragma unroll
    for (int kk = 0; kk < 16; ++kk) {
        short8 a[2];
#pragma unroll
        for (int rt = 0; rt < 2; ++rt)
            a[rt] = *(const short8*)((const char*)A1 + swz(rt * 16 + l15, kk * 64 + khalf * 16));
        short8 b[3][2];
#pragma unroll
        for (int g = 0; g < 3; ++g)
#pragma unroll
            for (int ct = 0; ct < 2; ++ct)
                b[g][ct] = *(const short8*)(b3p[g][ct] + kk * 32);
#pragma unroll
        for (int g = 0; g < 3; ++g)
#pragma unroll
            for (int rt = 0; rt < 2; ++rt)
#pragma unroll
                for (int ct = 0; ct < 2; ++ct)
                    acc3[g][rt][ct] = __builtin_amdgcn_mfma_f32_16x16x32_bf16(
                        a[rt], b[g][ct], acc3[g][rt][ct], 0, 0, 0);
    }

    // epilogue: out = z_l.*left + z_r.*right + z.*h_tilde  (x from A1 bf16)
#pragma unroll
    for (int ct = 0; ct < 2; ++ct) {
        int col = col0 + ct * 16 + l15;
        float bzl = pb[2 * H + col];
        float bzr = pb[3 * H + col];
        float bzz = pb[4 * H + col];
#pragma unroll
        for (int rt = 0; rt < 2; ++rt)
#pragma unroll
            for (int j = 0; j < 4; ++j) {
                int row = rt * 16 + khalf * 4 + j;
                int gr = n0 + row;
                if (gr < N) {
                    float zl = sigm(acc3[0][rt][ct][j] + bzl);
                    float zr = sigm(acc3[1][rt][ct][j] + bzr);
                    float zz = sigm(acc3[2][rt][ct][j] + bzz);
                    float xl = bf2f(*(const short*)((const char*)A1 + swz(row, col * 2)));
                    float xr = bf2f(*(const short*)((const char*)A1 + swz(row, (col + 256) * 2)));
                    curOut[(size_t)gr * H + col] = zl * xl + zr * xr + zz * ht[rt][ct][j];
                }
            }
    }
}

// ---------------- finalize: out = (h,h,h) ----------------
__global__ void finalize_kernel(const float* __restrict__ h, float* __restrict__ out) {
    int i = threadIdx.x;
    if (i < 768) out[i] = h[i & 255];
}

extern "C" void kernel_launch(void* const* d_in, const int* in_sizes, int n_in,
                              void* d_out, int out_size, void* d_ws, size_t ws_size,
                              hipStream_t stream) {
    const int*   tokens = (const int*)d_in[0];
    const float* emb    = (const float*)d_in[1];
    const float* WL     = (const float*)d_in[2];
    const float* WR     = (const float*)d_in[3];
    const float* bL     = (const float*)d_in[4];
    const float* bR     = (const float*)d_in[5];
    const float* Wlh    = (const float*)d_in[6];
    const float* Wrh    = (const float*)d_in[7];
    const float* blh    = (const float*)d_in[8];
    const float* brh    = (const float*)d_in[9];

    char* ws = (char*)d_ws;
    short* W1 = (short*)ws;                    // 5*256*512 bf16
    short* W2 = W1 + 5 * HK2;                  // 256*512 bf16
    float* pb = (float*)(W2 + HK2);            // 5*256 f32
    float* hb = pb + 5 * H;                    // 256 f32
    float* bufB = (float*)(ws + 2 * 1024 * 1024);   // 32768*256 f32
    float* bufA = bufB + (size_t)32768 * H;         // 16384*256 f32

    {
        int total = 5 * HK2 + HK2 + 5 * H + H;
        int blocks = (total + 255) / 256;
        prep_kernel<<<blocks, 256, 0, stream>>>(WL, WR, Wlh, Wrh, bL, bR, blh, brh,
                                                W1, W2, pb, hb);
    }

    // all 16 levels as separate launches
    const float* in = nullptr;
    for (int l = 0; l < 16; ++l) {
        int N = 32768 >> l;
        float* out = (l & 1) ? bufA : bufB;
        int blocks = (N + BM - 1) / BM;
        level_kernel<<<blocks, THREADS, 0, stream>>>(
            in, (l == 0) ? tokens : nullptr, emb, out, W1, W2, pb, hb, N);
        in = out;
    }

    finalize_kernel<<<1, 768, 0, stream>>>(bufA, (float*)d_out);
}